// Round 9
// baseline (338.387 us; speedup 1.0000x reference)
//
#include <hip/hip_runtime.h>
#include <hip/hip_bf16.h>
#include <math.h>

typedef unsigned short u16;   // bf16 storage
typedef __attribute__((ext_vector_type(8))) short s8v;    // 8 bf16 = 4 VGPR
typedef __attribute__((ext_vector_type(4))) float f4v;    // MFMA acc

#define B_    8
#define C_    64
#define HW_   4096
#define NPIX  32768     // B_*HW_
#define DI    128
#define NCH   256
#define CHL   16        // HW_/NCH

__device__ __forceinline__ float b2f(u16 v){ return __uint_as_float(((unsigned)v)<<16); }
__device__ __forceinline__ u16 f2b(float x){
  unsigned u = __float_as_uint(x);
  u += 0x7fff + ((u >> 16) & 1);      // RTNE
  return (u16)(u >> 16);
}
__device__ __forceinline__ float gelu_exact(float x){ return 0.5f*x*(1.0f+erff(x*0.70710678118654752f)); }
__device__ __forceinline__ float leaky02(float x){ return x>0.f ? x : 0.2f*x; }
__device__ __forceinline__ float softplus_(float x){ return fmaxf(x,0.f)+log1pf(__expf(-fabsf(x))); }
__device__ __forceinline__ float silu_(float x){ return x / (1.0f + __expf(-x)); }
__device__ __forceinline__ void unpack16(uint4 q0, uint4 q1, float* v){
  unsigned w[8]={q0.x,q0.y,q0.z,q0.w,q1.x,q1.y,q1.z,q1.w};
  #pragma unroll
  for(int j=0;j<8;j++){
    v[2*j]   = __uint_as_float(w[j]<<16);
    v[2*j+1] = __uint_as_float(w[j]&0xffff0000u);
  }
}

// ====== prep: all weights -> bf16 transposed [COUT][CIN]; W2 fused (xproj/dtw) ======
__global__ void k_prep(const float* __restrict__ vin_w1, const float* __restrict__ vin_w2,
                       const float* __restrict__ ssm_in_w, const float* __restrict__ xproj,
                       const float* __restrict__ dtw, const float* __restrict__ ssm_outw,
                       const float* __restrict__ ff_w1, const float* __restrict__ ff_w2,
                       u16* __restrict__ wv1, u16* __restrict__ wv2, u16* __restrict__ wsi,
                       u16* __restrict__ wdb, u16* __restrict__ wout, u16* __restrict__ wf1,
                       u16* __restrict__ wf2t){
  int g = blockIdx.x*256 + threadIdx.x;     // 80*256 = 20480
  if(g < 4096){
    int n=g>>6, c=g&63;
    wv1[n*64+c]=f2b(vin_w1[c*64+n]);
    wv2[n*64+c]=f2b(vin_w2[c*64+n]);
  }
  if(g < 16384){
    int n=g>>6, c=g&63;
    wsi[n*64+c]=f2b(ssm_in_w[c*256+n]);
    wf1[n*64+c]=f2b(ff_w1[c*256+n]);
    int n2=g/256, k2=g%256;
    wf2t[n2*256+k2]=f2b(ff_w2[k2*64+n2]);
  }
  if(g < 8192){
    int n=g>>7, k=g&127;
    wout[n*128+k]=f2b(ssm_outw[k*64+n]);
  }
  if(g < 20480){
    int n=g/128, k=g%128;
    float v;
    if(n < 128){
      v = 0.f;
      for(int r=0;r<4;r++) v += xproj[k*36+r]*dtw[r*128+n];
    }else{
      v = xproj[k*36+4+(n-128)];
    }
    wdb[n*128+k]=f2b(v);
  }
}

// ====== fused: NCHW fp32 -> (xT bf16 NHWC) + LayerNorm + vin_w1 MFMA -> outp ======
__global__ __launch_bounds__(256) void k_trans_ln_mm(const float* __restrict__ x,
                     const float* __restrict__ g, const float* __restrict__ bta,
                     const u16* __restrict__ wT,
                     u16* __restrict__ xT, u16* __restrict__ outp){
  const int LDA = 72, NS = 4;
  __shared__ float tile[64][65];
  __shared__ __align__(16) u16 sA[64*LDA];
  __shared__ __align__(16) u16 sW[64*LDA];
  int tid = threadIdx.x;
  int blk = blockIdx.x;            // 512
  int b = blk >> 6;
  int hwb = (blk & 63) << 6;
  int lane = tid & 63, row = tid >> 6;
  const float* src = x + (size_t)b*C_*HW_;
  #pragma unroll
  for(int k=0;k<16;k++){
    int c = row + 4*k;
    tile[c][lane] = src[c*HW_ + hwb + lane];
  }
  for(int idx=tid; idx<64*8; idx+=256){
    int n = idx>>3, c8 = (idx&7)*8;
    *(uint4*)(sW + n*LDA + c8) = *(const uint4*)(wT + n*64 + c8);
  }
  __syncthreads();
  u16* dstT = xT + (size_t)b*HW_*C_;
  #pragma unroll
  for(int k=0;k<16;k++){
    int hwl = row + 4*k;
    dstT[(hwb+hwl)*C_ + lane] = f2b(tile[lane][hwl]);
  }
  float gg = g[lane], bb = bta[lane];
  #pragma unroll
  for(int i=0;i<16;i++){
    int hwl = row*16 + i;
    float v = tile[lane][hwl];
    float s = v, sq = v*v;
    #pragma unroll
    for(int o=32;o>0;o>>=1){ s += __shfl_xor(s,o); sq += __shfl_xor(sq,o); }
    float m = s*(1.f/64.f);
    float var = sq*(1.f/64.f) - m*m;
    float r = rsqrtf(var + 1e-5f);
    sA[hwl*LDA + lane] = f2b((v-m)*r*gg + bb);
  }
  __syncthreads();
  int ln = tid & 63, wv = tid >> 6;
  int mrow = ln & 15, quad = ln >> 4;
  f4v acc[NS];
  #pragma unroll
  for(int i=0;i<NS;i++) acc[i] = (f4v){0.f,0.f,0.f,0.f};
  const u16* aBase = sA + (wv*16 + mrow)*LDA + quad*8;
  const u16* wBase = sW + mrow*LDA + quad*8;
  #pragma unroll
  for(int kk=0; kk<64; kk+=32){
    s8v af = *(const s8v*)(aBase + kk);
    #pragma unroll
    for(int ns=0; ns<NS; ns++){
      s8v bf = *(const s8v*)(wBase + ns*16*LDA + kk);
      acc[ns] = __builtin_amdgcn_mfma_f32_16x16x32_bf16(af, bf, acc[ns], 0, 0, 0);
    }
  }
  int p0 = blk*64;
  int pr = p0 + wv*16 + quad*4;
  #pragma unroll
  for(int ns=0; ns<NS; ns++){
    int n = ns*16 + mrow;
    #pragma unroll
    for(int r=0;r<4;r++)
      outp[(size_t)(pr+r)*64 + n] = f2b(acc[ns][r]);
  }
}

// ====== fused vin: dw3+gelu + 1x1 (wv2) MFMA; 512 blocks, 8x8 tile ======
__global__ __launch_bounds__(256) void k_dw3mm(const u16* __restrict__ in,
                     const float* __restrict__ dwgt, const u16* __restrict__ wT,
                     u16* __restrict__ x0){
  const int LDT = 72;
  __shared__ __align__(16) u16 sIn[10*10*64];    // 12.8 KB
  __shared__ __align__(16) u16 sT[64*LDT];       // 9.2 KB
  __shared__ __align__(16) u16 sW[64*LDT];       // 9.2 KB
  int tid = threadIdx.x;
  int blk = blockIdx.x;            // 512
  int b = blk >> 6;
  int t6 = blk & 63;
  int h0 = (t6 >> 3) * 8, w0 = (t6 & 7) * 8;
  for(int idx=tid; idx<64*8; idx+=256){
    int n = idx>>3, c8 = (idx&7)*8;
    *(uint4*)(sW + n*LDT + c8) = *(const uint4*)(wT + n*64 + c8);
  }
  for(int q=tid; q<10*10*16; q+=256){
    int pp = q >> 4, c4 = q & 15;
    int hh = pp / 10, ww = pp % 10;
    int gh = h0-1+hh, gw = w0-1+ww;
    ushort4 v = make_ushort4(0,0,0,0);
    if((unsigned)gh < 64u && (unsigned)gw < 64u)
      v = *(const ushort4*)(in + (size_t)((b*64+gh)*64+gw)*64 + c4*4);
    *(ushort4*)(sIn + pp*64 + c4*4) = v;
  }
  __syncthreads();
  int c4 = tid & 15;
  #pragma unroll
  for(int pass=0; pass<4; pass++){
    int opix = pass*16 + (tid>>4);
    int oh = opix >> 3, ow = opix & 7;
    float a0=0.f,a1=0.f,a2=0.f,a3=0.f;
    #pragma unroll
    for(int kh=0;kh<3;kh++){
      #pragma unroll
      for(int kw=0;kw<3;kw++){
        ushort4 v = *(const ushort4*)(sIn + ((oh+kh)*10 + (ow+kw))*64 + c4*4);
        float4 wv = *(const float4*)(dwgt + (kh*3+kw)*64 + c4*4);
        a0 += b2f(v.x)*wv.x; a1 += b2f(v.y)*wv.y;
        a2 += b2f(v.z)*wv.z; a3 += b2f(v.w)*wv.w;
      }
    }
    ushort4 o; o.x=f2b(gelu_exact(a0)); o.y=f2b(gelu_exact(a1));
    o.z=f2b(gelu_exact(a2)); o.w=f2b(gelu_exact(a3));
    *(ushort4*)(sT + opix*LDT + c4*4) = o;
  }
  __syncthreads();
  int ln = tid & 63, wv = tid >> 6;
  int mrow = ln & 15, quad = ln >> 4;
  f4v acc[4];
  #pragma unroll
  for(int i=0;i<4;i++) acc[i] = (f4v){0.f,0.f,0.f,0.f};
  const u16* aBase = sT + (wv*16 + mrow)*LDT + quad*8;
  const u16* wBase = sW + mrow*LDT + quad*8;
  #pragma unroll
  for(int kk=0; kk<64; kk+=32){
    s8v af = *(const s8v*)(aBase + kk);
    #pragma unroll
    for(int ns=0; ns<4; ns++){
      s8v bf = *(const s8v*)(wBase + ns*16*LDT + kk);
      acc[ns] = __builtin_amdgcn_mfma_f32_16x16x32_bf16(af, bf, acc[ns], 0, 0, 0);
    }
  }
  #pragma unroll
  for(int ns=0; ns<4; ns++){
    int n = ns*16 + mrow;
    #pragma unroll
    for(int r=0;r<4;r++){
      int opix = wv*16 + quad*4 + r;
      int oh = opix >> 3, ow = opix & 7;
      size_t p = ((size_t)(b*64 + h0+oh)*64 + (w0+ow));
      x0[p*64 + n] = f2b(acc[ns][r]);
    }
  }
}

// ====== fused: ssm_in matmul + causal conv + silu + dt/bc MFMA ======
// v2: MFMA A/B fragments direct from global (single-use; L2-hot) — LDS only for
// ubuf + xiT (true reuse). LDS 63.2 -> 34.6 KB, barriers 5 -> 2, 4 blocks/CU.
__global__ __launch_bounds__(256, 4) void k_ssm_dtbc(const u16* __restrict__ wT,
                     const u16* __restrict__ x0,
                     const float* __restrict__ cw, const float* __restrict__ cb,
                     const u16* __restrict__ wdb, const float* __restrict__ dtbias,
                     u16* __restrict__ xi, u16* __restrict__ zs,
                     u16* __restrict__ dtout, u16* __restrict__ bcout){
  const int NS=16, LDY=136, NS2=10;
  __shared__ __align__(16) u16 S[17280];   // 34.6 KB
  u16* ubuf = S;            // [67][128]
  u16* xiT  = S + 8576;     // [64][136]
  int tid = threadIdx.x;
  int p0 = blockIdx.x*64;
  int ln = tid & 63, wv = tid >> 6;
  int mrow = ln & 15, quad = ln >> 4;
  // MFMA1: u = x0-tile @ wsi^T; fragments direct from global (each address used once)
  f4v acc[NS];
  #pragma unroll
  for(int i=0;i<NS;i++) acc[i] = (f4v){0.f,0.f,0.f,0.f};
  const u16* aRow = x0 + (size_t)(p0 + wv*16 + mrow)*64 + quad*8;
  #pragma unroll
  for(int kk=0; kk<64; kk+=32){
    s8v af = *(const s8v*)(aRow + kk);
    #pragma unroll
    for(int ns=0; ns<NS; ns++){
      s8v bf = *(const s8v*)(wT + (size_t)(ns*16 + mrow)*64 + kk + quad*8);
      acc[ns] = __builtin_amdgcn_mfma_f32_16x16x32_bf16(af, bf, acc[ns], 0, 0, 0);
    }
  }
  // causal-conv halo rows u[-3..-1]: vectorized global dot (same c-order as before)
  bool bstart = ((p0 & 4095) == 0);
  for(int idx=tid; idx<384; idx+=256){
    int j = idx >> 7, n = idx & 127;
    float a2 = 0.f;
    if(!bstart){
      const u16* xr = x0 + (size_t)(p0-3+j)*64;
      const u16* wr = wT + (size_t)n*64;
      #pragma unroll
      for(int c8=0;c8<64;c8+=8){
        s8v xv = *(const s8v*)(xr + c8);
        s8v wv8 = *(const s8v*)(wr + c8);
        #pragma unroll
        for(int jj=0;jj<8;jj++) a2 += b2f((u16)xv[jj]) * b2f((u16)wv8[jj]);
      }
    }
    ubuf[j*128 + n] = f2b(a2);
  }
  int prl = wv*16 + quad*4;
  #pragma unroll
  for(int ns=0; ns<NS; ns++){
    int n = ns*16 + mrow;
    if(n < 128){
      #pragma unroll
      for(int r=0;r<4;r++) ubuf[(prl+r+3)*128 + n] = f2b(acc[ns][r]);
    }else{
      #pragma unroll
      for(int r=0;r<4;r++) zs[(size_t)(p0+prl+r)*128 + (n-128)] = f2b(silu_(acc[ns][r]));
    }
  }
  __syncthreads();   // ubuf complete
  int d4 = tid & 31;
  float4 cbv = *(const float4*)(cb + d4*4);
  for(int row = tid >> 5; row < 64; row += 8){
    float a0=cbv.x, a1=cbv.y, a2=cbv.z, a3=cbv.w;
    #pragma unroll
    for(int k=0;k<4;k++){
      ushort4 v = *(const ushort4*)(ubuf + (row+k)*128 + d4*4);
      float4 wv4 = *(const float4*)(cw + k*128 + d4*4);
      a0 += b2f(v.x)*wv4.x; a1 += b2f(v.y)*wv4.y;
      a2 += b2f(v.z)*wv4.z; a3 += b2f(v.w)*wv4.w;
    }
    ushort4 o; o.x=f2b(silu_(a0)); o.y=f2b(silu_(a1)); o.z=f2b(silu_(a2)); o.w=f2b(silu_(a3));
    *(ushort4*)(xi + (size_t)(p0+row)*128 + d4*4) = o;
    *(ushort4*)(xiT + row*LDY + d4*4) = o;
  }
  __syncthreads();   // xiT complete
  // MFMA2: A from xiT (LDS), B direct from global wdb (single-use fragments)
  f4v acc2[NS2];
  #pragma unroll
  for(int i=0;i<NS2;i++) acc2[i] = (f4v){0.f,0.f,0.f,0.f};
  #pragma unroll
  for(int kk=0; kk<128; kk+=32){
    s8v af = *(const s8v*)(xiT + (wv*16+mrow)*LDY + kk + quad*8);
    #pragma unroll
    for(int ns=0; ns<NS2; ns++){
      s8v bf = *(const s8v*)(wdb + (size_t)(ns*16+mrow)*128 + kk + quad*8);
      acc2[ns] = __builtin_amdgcn_mfma_f32_16x16x32_bf16(af, bf, acc2[ns], 0, 0, 0);
    }
  }
  int pr = p0 + prl;
  #pragma unroll
  for(int ns=0; ns<NS2; ns++){
    int n = ns*16 + mrow;
    if(n < 128){
      float bs = dtbias[n];
      #pragma unroll
      for(int r=0;r<4;r++)
        dtout[(size_t)(pr+r)*128 + n] = f2b(softplus_(acc2[ns][r] + bs));
    }else{
      #pragma unroll
      for(int r=0;r<4;r++)
        bcout[(size_t)(pr+r)*32 + (n-128)] = f2b(acc2[ns][r]);
    }
  }
}

// ====== scan phase 1: LDS-free, 1 chunk/thread, high occupancy ======
__global__ __launch_bounds__(256) void k_scan1(const u16* __restrict__ dt, const u16* __restrict__ xi,
                        const u16* __restrict__ bc, const float* __restrict__ alog,
                        u16* __restrict__ Pb, u16* __restrict__ Qb){
  int t = blockIdx.x*256 + threadIdx.x;    // 1024 blocks
  int d = t & 127;
  int ch = (t >> 7) & 255;
  int b = t >> 15;
  int pbase = b*HW_ + ch*CHL;
  float A[16];
  #pragma unroll
  for(int s=0;s<16;s++) A[s] = -__expf(alog[d*16+s]);
  float dtv[16], uv[16];
  #pragma unroll
  for(int i=0;i<CHL;i++){
    dtv[i] = b2f(dt[(size_t)(pbase+i)*128 + d]);
    uv[i]  = dtv[i] * b2f(xi[(size_t)(pbase+i)*128 + d]);
  }
  float Q[16], sumdt = 0.f;
  #pragma unroll
  for(int s=0;s<16;s++) Q[s] = 0.f;
  #pragma unroll
  for(int i=0;i<CHL;i++){
    float Bv[16];
    unpack16(*(const uint4*)(bc + (size_t)(pbase+i)*32),
             *(const uint4*)(bc + (size_t)(pbase+i)*32 + 8), Bv);
    sumdt += dtv[i];
    #pragma unroll
    for(int s=0;s<16;s++){
      float a = __expf(dtv[i]*A[s]);
      Q[s] = a*Q[s] + uv[i]*Bv[s];
    }
  }
  int gidx = ch*16384 + (b*128+d)*16;
  unsigned pw[8], qw[8];
  #pragma unroll
  for(int j=0;j<8;j++){
    pw[j] = (unsigned)f2b(__expf(A[2*j]*sumdt)) | ((unsigned)f2b(__expf(A[2*j+1]*sumdt))<<16);
    qw[j] = (unsigned)f2b(Q[2*j]) | ((unsigned)f2b(Q[2*j+1])<<16);
  }
  *(uint4*)(Pb+gidx)   = make_uint4(pw[0],pw[1],pw[2],pw[3]);
  *(uint4*)(Pb+gidx+8) = make_uint4(pw[4],pw[5],pw[6],pw[7]);
  *(uint4*)(Qb+gidx)   = make_uint4(qw[0],qw[1],qw[2],qw[3]);
  *(uint4*)(Qb+gidx+8) = make_uint4(qw[4],qw[5],qw[6],qw[7]);
}

// ---------------- scan phase 2: block-level 2-pass affine scan ----------------
__global__ __launch_bounds__(256) void k_scan2(const u16* __restrict__ Pb, const u16* __restrict__ Qb,
                        u16* __restrict__ Hin){
  __shared__ __align__(16) u16 sP[256*32];   // 16 KB
  __shared__ __align__(16) u16 sQ[256*32];   // 16 KB
  __shared__ float gP[8*32];
  __shared__ float gQ[8*32];
  int tid = threadIdx.x;
  int s0 = blockIdx.x * 32;                  // 512 blocks over 16384 sequences
  for(int idx = tid; idx < 256*4; idx += 256){
    int ch = idx >> 2, j8 = (idx & 3) * 8;
    *(uint4*)(sP + ch*32 + j8) = *(const uint4*)(Pb + (size_t)ch*16384 + s0 + j8);
    *(uint4*)(sQ + ch*32 + j8) = *(const uint4*)(Qb + (size_t)ch*16384 + s0 + j8);
  }
  __syncthreads();
  int sl = tid & 31, grp = tid >> 5;         // 8 groups x 32 chunks each
  int base = grp * 32;
  float P = 1.f, Q = 0.f;
  #pragma unroll 8
  for(int c = 0; c < 32; c++){
    float p = b2f(sP[(base+c)*32 + sl]);
    float q = b2f(sQ[(base+c)*32 + sl]);
    P = p * P;
    Q = p * Q + q;
  }
  gP[grp*32 + sl] = P;
  gQ[grp*32 + sl] = Q;
  __syncthreads();
  float h = 0.f;                             // exclusive group prefix (h0 = 0)
  #pragma unroll
  for(int g = 0; g < 7; g++){
    if(g < grp) h = gP[g*32 + sl] * h + gQ[g*32 + sl];
  }
  for(int c = 0; c < 32; c++){
    Hin[(size_t)(base+c)*16384 + s0 + sl] = f2b(h);
    float p = b2f(sP[(base+c)*32 + sl]);
    float q = b2f(sQ[(base+c)*32 + sl]);
    h = p * h + q;
  }
}

// ------- scan phase 3 (global column loads) + out-proj MFMA -------
__global__ __launch_bounds__(128) void k_scan3_mm(const u16* __restrict__ dt, const u16* __restrict__ xi,
                        const u16* __restrict__ bc, const u16* __restrict__ zs,
                        const float* __restrict__ alog, const float* __restrict__ Dp,
                        const u16* __restrict__ Hin, const u16* __restrict__ wout,
                        const u16* __restrict__ x0, u16* __restrict__ y){
  const int LDY = 136, LDW = 136;
  int blk = blockIdx.x;
  int ch = blk & (NCH-1);
  int b = blk >> 8;
  int d = threadIdx.x, tid = threadIdx.x;
  __shared__ __align__(16) u16 sY[CHL*LDY];
  __shared__ __align__(16) u16 sWo[64*LDW];
  __shared__ __align__(16) u16 sbc[CHL*32];
  for(int idx=tid; idx<64*16; idx+=128){
    int n = idx>>4, c8 = (idx&15)*8;
    *(uint4*)(sWo + n*LDW + c8) = *(const uint4*)(wout + n*128 + c8);
  }
  int pbase = b*HW_ + ch*CHL;
  if(tid < 64) ((uint4*)sbc)[tid] = ((const uint4*)(bc + (size_t)pbase*32))[tid];
  float A[16], h[16];
  u16 hbuf[16];
  int gidx = ch*16384 + (b*128+d)*16;
  *(uint4*)hbuf     = *(const uint4*)(Hin+gidx);
  *(uint4*)(hbuf+8) = *(const uint4*)(Hin+gidx+8);
  #pragma unroll
  for(int s=0;s<16;s++){ A[s] = -__expf(alog[d*16+s]); h[s] = b2f(hbuf[s]); }
  float Dd = Dp[d];
  float dtv[16], xiv[16], zsv[16];
  #pragma unroll
  for(int i=0;i<CHL;i++){
    dtv[i] = b2f(dt[(size_t)(pbase+i)*128 + d]);
    xiv[i] = b2f(xi[(size_t)(pbase+i)*128 + d]);
    zsv[i] = b2f(zs[(size_t)(pbase+i)*128 + d]);
  }
  __syncthreads();
  #pragma unroll
  for(int i=0;i<CHL;i++){
    float Bv[16], Cv[16];
    unpack16(*(const uint4*)(sbc + i*32),      *(const uint4*)(sbc + i*32 + 8),  Bv);
    unpack16(*(const uint4*)(sbc + i*32 + 16), *(const uint4*)(sbc + i*32 + 24), Cv);
    float u = dtv[i]*xiv[i];
    float acc = Dd*xiv[i];
    #pragma unroll
    for(int s=0;s<16;s++){
      float a = __expf(dtv[i]*A[s]);
      h[s] = a*h[s] + u*Bv[s];
      acc += h[s]*Cv[s];
    }
    sY[i*LDY + d] = f2b(acc * zsv[i]);
  }
  __syncthreads();
  int ln = tid & 63, wv = tid >> 6;
  int mrow = ln & 15, quad = ln >> 4;
  f4v acc2[2];
  acc2[0] = (f4v){0.f,0.f,0.f,0.f};
  acc2[1] = (f4v){0.f,0.f,0.f,0.f};
  #pragma unroll
  for(int kk=0; kk<128; kk+=32){
    s8v af = *(const s8v*)(sY + mrow*LDY + kk + quad*8);
    #pragma unroll
    for(int ns=0; ns<2; ns++){
      int n0 = wv*32 + ns*16;
      s8v bf = *(const s8v*)(sWo + (n0+mrow)*LDW + kk + quad*8);
      acc2[ns] = __builtin_amdgcn_mfma_f32_16x16x32_bf16(af, bf, acc2[ns], 0, 0, 0);
    }
  }
  #pragma unroll
  for(int ns=0; ns<2; ns++){
    int n = wv*32 + ns*16 + mrow;
    #pragma unroll
    for(int r=0;r<4;r++){
      int px = pbase + quad*4 + r;
      y[(size_t)px*64 + n] = f2b(acc2[ns][r] + b2f(x0[(size_t)px*64 + n]));
    }
  }
}

// ====== fully-fused tail v4: vout + FFN, 512 thr, FAT phases (7 barriers) ======
__global__ __launch_bounds__(512, 4) void k_ffn2(const u16* __restrict__ yin,
                     const float* __restrict__ w1, const float* __restrict__ w2,
                     const u16* __restrict__ xTr,
                     const float* __restrict__ g, const float* __restrict__ bta,
                     const u16* __restrict__ wf1, const u16* __restrict__ wf2t,
                     const float* __restrict__ fdw,
                     u16* __restrict__ xrout, float* __restrict__ outp){
  const int LDX = 72, LDT = 264;
  extern __shared__ __align__(16) u16 S[];
  u16* sX   = S;                    // [112][72]  raw xR then LN'd (rows 100..111 zero)
  u16* sT1  = S + 8064;             // [112][264] t1 full (phase 2)           59136 B
  u16* sYh  = S + 8064;             // [196][72]  y halo 14x14 (phase 1, aliases sT1)
  u16* sT   = S + 22176;            // [144][72]  t = gelu(dw1(y)) (phase 1)
  float* red = (float*)S;           // [64][64] f32 (after final barrier; aliases sX+t1 head)
  int tid = threadIdx.x;
  int blk = blockIdx.x;             // 512
  int b = blk >> 6;
  int t6 = blk & 63;
  int h0 = (t6 >> 3)*8, w0 = (t6 & 7)*8;
  int ln = tid & 63, wv = tid >> 6;         // wv 0..7
  int mrow = ln & 15, quad = ln >> 4;
  // phase 1a: load y 14x14 halo (zero outside image)
  for(int q=tid; q<196*16; q+=512){
    int pp = q >> 4, c4 = q & 15;
    int hh = pp / 14, ww = pp - hh*14;
    int gh = h0-3+hh, gw = w0-3+ww;
    ushort4 v = make_ushort4(0,0,0,0);
    if((unsigned)gh < 64u && (unsigned)gw < 64u)
      v = *(const ushort4*)(yin + (size_t)((b*64+gh)*64+gw)*64 + c4*4);
    *(ushort4*)(sYh + pp*LDX + c4*4) = v;
  }
  __syncthreads();
  // phase 1b: t = gelu(dw1(y)) on 12x12 (0 outside image)
  for(int q=tid; q<144*16; q+=512){
    int tpix = q >> 4, c4 = q & 15;
    int th = tpix / 12, tw = tpix - th*12;
    int gh = h0-2+th, gw = w0-2+tw;
    ushort4 o = make_ushort4(0,0,0,0);
    if((unsigned)gh < 64u && (unsigned)gw < 64u){
      float a0=0.f,a1=0.f,a2=0.f,a3=0.f;
      #pragma unroll
      for(int kh=0;kh<3;kh++){
        #pragma unroll
        for(int kw=0;kw<3;kw++){
          ushort4 v = *(const ushort4*)(sYh + ((th+kh)*14 + (tw+kw))*LDX + c4*4);
          float4 wv4 = *(const float4*)(w1 + (kh*3+kw)*64 + c4*4);
          a0 += b2f(v.x)*wv4.x; a1 += b2f(v.y)*wv4.y;
          a2 += b2f(v.z)*wv4.z; a3 += b2f(v.w)*wv4.w;
        }
      }
      o.x=f2b(gelu_exact(a0)); o.y=f2b(gelu_exact(a1));
      o.z=f2b(gelu_exact(a2)); o.w=f2b(gelu_exact(a3));
    }
    *(ushort4*)(sT + tpix*LDX + c4*4) = o;
  }
  __syncthreads();
  // phase 1c: raw xR = dw2(t)+y+xT on 10x10 -> sX; center 8x8 -> global xrout
  for(int q=tid; q<100*16; q+=512){
    int xpix = q >> 4, c4 = q & 15;
    int xh = xpix / 10, xw = xpix - xh*10;
    int gh = h0-1+xh, gw = w0-1+xw;
    ushort4 o = make_ushort4(0,0,0,0);
    if((unsigned)gh < 64u && (unsigned)gw < 64u){
      float a0=0.f,a1=0.f,a2=0.f,a3=0.f;
      #pragma unroll
      for(int kh=0;kh<3;kh++){
        #pragma unroll
        for(int kw=0;kw<3;kw++){
          ushort4 v = *(const ushort4*)(sT + ((xh+kh)*12 + (xw+kw))*LDX + c4*4);
          float4 wv4 = *(const float4*)(w2 + (kh*3+kw)*64 + c4*4);
          a0 += b2f(v.x)*wv4.x; a1 += b2f(v.y)*wv4.y;
          a2 += b2f(v.z)*wv4.z; a3 += b2f(v.w)*wv4.w;
        }
      }
      ushort4 ry = *(const ushort4*)(sYh + ((xh+2)*14 + (xw+2))*LDX + c4*4);
      ushort4 rx = *(const ushort4*)(xTr + ((size_t)(b*64+gh)*64+gw)*64 + c4*4);
      a0 += b2f(ry.x) + b2f(rx.x);
      a1 += b2f(ry.y) + b2f(rx.y);
      a2 += b2f(ry.z) + b2f(rx.z);
      a3 += b2f(ry.w) + b2f(rx.w);
      o.x=f2b(a0); o.y=f2b(a1); o.z=f2b(a2); o.w=f2b(a3);
    }
    *(ushort4*)(sX + xpix*LDX + c4*4) = o;
    if(xh>=1 && xh<=8 && xw>=1 && xw<=8)
      *(ushort4*)(xrout + ((size_t)(b*64+gh)*64+gw)*64 + c4*4) = o;
  }
  __syncthreads();
  // LN sX in place (8 waves, stride 8)
  float gg = g[ln], bb = bta[ln];
  for(int hp = wv; hp < 112; hp += 8){
    u16 o = 0;
    if(hp < 100){
      int th = hp/10, tw = hp - th*10;
      int gh = h0-1+th, gw = w0-1+tw;
      if((unsigned)gh < 64u && (unsigned)gw < 64u){
        float v = b2f(sX[hp*LDX + ln]);
        float s = v, sq = v*v;
        #pragma unroll
        for(int o2=32;o2>0;o2>>=1){ s += __shfl_xor(s,o2); sq += __shfl_xor(sq,o2); }
        float m = s*(1.f/64.f);
        float var = sq*(1.f/64.f) - m*m;
        float r = rsqrtf(var + 1e-5f);
        o = f2b((v-m)*r*gg + bb);
      }
    }
    sX[hp*LDX + ln] = o;
  }
  __syncthreads();
  // phase 2a: MFMA1 for ALL chunks -> t1full; 28 tasks (7 mt x 4 chunks) over 8 waves
  for(int t = wv; t < 28; t += 8){
    int mt = t % 7, ck = t / 7;
    int nc0 = ck*64;
    f4v a1[4];
    #pragma unroll
    for(int i=0;i<4;i++) a1[i] = (f4v){0.f,0.f,0.f,0.f};
    const u16* aB = sX + (mt*16 + mrow)*LDX + quad*8;
    #pragma unroll
    for(int kk=0; kk<64; kk+=32){
      s8v af = *(const s8v*)(aB + kk);
      #pragma unroll
      for(int ns=0; ns<4; ns++){
        s8v bf = *(const s8v*)(wf1 + (size_t)(nc0 + ns*16 + mrow)*64 + kk + quad*8);
        a1[ns] = __builtin_amdgcn_mfma_f32_16x16x32_bf16(af, bf, a1[ns], 0, 0, 0);
      }
    }
    #pragma unroll
    for(int ns=0; ns<4; ns++)
      #pragma unroll
      for(int r=0; r<4; r++)
        sT1[(mt*16 + quad*4 + r)*LDT + nc0 + ns*16 + mrow] = f2b(leaky02(a1[ns][r]));
  }
  __syncthreads();
  // phase 2b: dw3 + leaky -> MFMA2 A-frags, all 4 chunks, no barriers; K-half per wave-group
  f4v acc2[4];
  #pragma unroll
  for(int i=0;i<4;i++) acc2[i] = (f4v){0.f,0.f,0.f,0.f};
  int grp = wv >> 2;                 // K-half owned by this wave group
  int pw = (wv & 3)*16 + mrow;       // dw pixel owned by this lane
  int oh = pw >> 3, ow = pw & 7;
  int chf = grp*32 + quad*8;         // K-slice channels within chunk
  #pragma unroll
  for(int ck=0; ck<4; ck++){
    int nc0 = ck*64;
    float a[8];
    #pragma unroll
    for(int j=0;j<8;j++) a[j] = 0.f;
    #pragma unroll
    for(int kh=0;kh<3;kh++){
      #pragma unroll
      for(int kw=0;kw<3;kw++){
        s8v v = *(const s8v*)(sT1 + ((oh+kh)*10 + (ow+kw))*LDT + nc0 + chf);
        const float* wp = fdw + (kh*3+kw)*256 + nc0 + chf;
        float4 w0v = *(const float4*)(wp);
        float4 w1v = *(const float4*)(wp+4);
        a[0] += b2f((u16)v[0])*w0v.x; a[1] += b2f((u16)v[1])*w0v.y;
        a[2] += b2f((u16)v[2])*w0v.z; a[3] += b2f((u16)v[3])*w0v.w;
        a[4] += b2f((u16)v[4])*w1v.x; a[5] += b2f((u16)v[5])*w1v.y;
        a[6] += b2f((u16)v[6])*w1v.z; a[7] += b2f((u16)v[7])*w1v.w;
      }
    }
    s8v af;
    #pragma unroll
    for(int j=0;j<8;j++) af[j] = (short)f2b(leaky02(a[j]));
    #pragma unroll
    for(int ns=0; ns<4; ns++){
      s8v bf = *(const s8v*)(wf2t + (size_t)(ns*16 + mrow)*256 + nc0 + chf);
      acc2[ns] = __builtin_amdgcn_mfma_f32_16x16x32_bf16(af, bf, acc2[ns], 0, 0, 0);
    }
  }
  __syncthreads();   // all t1 reads done before red (aliases sX/t1 head) is written
  // epilogue: reduce K-half partials, add residual (global, L2-hot), store fp32 NCHW
  int pe = (wv & 3)*16 + quad*4;
  if(grp == 1){
    #pragma unroll
    for(int ns=0; ns<4; ns++){
      int n = ns*16 + mrow;
      #pragma unroll
      for(int r=0;r<4;r++) red[(pe+r)*64 + n] = acc2[ns][r];
    }
  }
  __syncthreads();
  if(grp == 0){
    int eoh = pe >> 3, eow0 = pe & 7;
    size_t gbase = (size_t)((b*64 + h0 + eoh)*64 + (w0 + eow0));
    #pragma unroll
    for(int ns=0; ns<4; ns++){
      int n = ns*16 + mrow;
      float4 v4;
      v4.x = acc2[ns][0] + red[(pe+0)*64 + n] + b2f(xrout[(gbase+0)*64 + n]);
      v4.y = acc2[ns][1] + red[(pe+1)*64 + n] + b2f(xrout[(gbase+1)*64 + n]);
      v4.z = acc2[ns][2] + red[(pe+2)*64 + n] + b2f(xrout[(gbase+2)*64 + n]);
      v4.w = acc2[ns][3] + red[(pe+3)*64 + n] + b2f(xrout[(gbase+3)*64 + n]);
      *(float4*)(outp + (size_t)b*C_*HW_ + (size_t)n*HW_ + (h0+eoh)*64 + (w0+eow0)) = v4;
    }
  }
}

extern "C" void kernel_launch(void* const* d_in, const int* in_sizes, int n_in,
                              void* d_out, int out_size, void* d_ws, size_t ws_size,
                              hipStream_t stream) {
  const float* x        = (const float*)d_in[0];
  const float* ln1_g    = (const float*)d_in[1];
  const float* ln1_b    = (const float*)d_in[2];
  const float* vin_w1   = (const float*)d_in[3];
  const float* vin_dw   = (const float*)d_in[4];
  const float* vin_w2   = (const float*)d_in[5];
  const float* vout_dw1 = (const float*)d_in[6];
  const float* vout_dw2 = (const float*)d_in[7];
  const float* ssm_in_w = (const float*)d_in[8];
  const float* ssm_cw   = (const float*)d_in[9];
  const float* ssm_cb   = (const float*)d_in[10];
  const float* ssm_xprj = (const float*)d_in[11];
  const float* ssm_dtw  = (const float*)d_in[12];
  const float* ssm_dtb  = (const float*)d_in[13];
  const float* ssm_Alog = (const float*)d_in[14];
  const float* ssm_D    = (const float*)d_in[15];
  const float* ssm_outw = (const float*)d_in[16];
  const float* ln2_g    = (const float*)d_in[17];
  const float* ln2_b    = (const float*)d_in[18];
  const float* ff_w1    = (const float*)d_in[19];
  const float* ff_dw    = (const float*)d_in[20];
  const float* ff_w2    = (const float*)d_in[21];
  float* out = (float*)d_out;

  // ---- bf16 arena, lifetime-packed (units: bf16 elements) ----
  const size_t M = 1u<<20;
  u16* U   = (u16*)d_ws;
  u16* xT  = U;              // [0,2M)
  u16* tA  = U + 2*M;        // [2M,4M)   Hin during scan
  u16* tB  = U + 4*M;        // [4M,6M)
  u16* x0  = U + 6*M;        // [6M,8M)   x0; later xR-center scratch for k_ffn2
  u16* xi  = U + 8*M;        // [8M,12M)
  u16* zs  = U + 12*M;       // [12M,16M)
  u16* dtb = U + 24*M;       // [24M,28M) dt
  u16* bc  = U + 28*M;       // [28M,29M)
  u16* Pb  = U + 16*M;       // [16M,20M)
  u16* Qb  = U + 20*M;       // [20M,24M)
  u16* Hin = tA;             // [2M,6M)
  u16* y   = U + 16*M;       // [16M,18M)
  // pre-transposed bf16 weights:
  u16* wv1  = U + 33*M;
  u16* wv2  = wv1 + 4096;
  u16* wsi  = wv2 + 4096;
  u16* wdb  = wsi + 16384;
  u16* wout = wdb + 20480;
  u16* wf1  = wout + 8192;
  u16* wf2t = wf1 + 16384;

  static bool attr_set = false;
  if(!attr_set){
    hipFuncSetAttribute((const void*)k_ffn2,
                        hipFuncAttributeMaxDynamicSharedMemorySize, 75264);
    attr_set = true;
  }

  k_prep<<<80,256,0,stream>>>(vin_w1, vin_w2, ssm_in_w, ssm_xprj, ssm_dtw, ssm_outw,
                              ff_w1, ff_w2, wv1, wv2, wsi, wdb, wout, wf1, wf2t);

  // --- vision in path (dw3+gelu+vin_w2 fused, 512 blocks) ---
  k_trans_ln_mm<<<512,256,0,stream>>>(x, ln1_g, ln1_b, wv1, xT, tB);
  k_dw3mm<<<512,256,0,stream>>>(tB, vin_dw, wv2, x0);

  // --- SSM (ssm_in + conv + dt/bc fused; scan1 standalone for occupancy) ---
  k_ssm_dtbc<<<512,256,0,stream>>>(wsi, x0, ssm_cw, ssm_cb, wdb, ssm_dtb,
                                   xi, zs, dtb, bc);
  k_scan1<<<1024,256,0,stream>>>(dtb, xi, bc, ssm_Alog, Pb, Qb);
  k_scan2<<<512,256,0,stream>>>(Pb, Qb, Hin);
  k_scan3_mm<<<2048,128,0,stream>>>(dtb, xi, bc, zs, ssm_Alog, ssm_D, Hin, wout, x0, y);

  // --- fused tail v4: vout + FFN, fat phases; x0 reused as xR-center scratch ---
  k_ffn2<<<512,512,75264,stream>>>(y, vout_dw1, vout_dw2, xT, ln2_g, ln2_b,
                                   wf1, wf2t, ff_dw, x0, out);
}

// Round 10
// 245.637 us; speedup vs baseline: 1.3776x; 1.3776x over previous
//
#include <hip/hip_runtime.h>
#include <hip/hip_bf16.h>
#include <math.h>

typedef unsigned short u16;   // bf16 storage
typedef __attribute__((ext_vector_type(8))) short s8v;    // 8 bf16 = 4 VGPR
typedef __attribute__((ext_vector_type(4))) float f4v;    // MFMA acc

#define B_    8
#define C_    64
#define HW_   4096
#define NPIX  32768     // B_*HW_
#define DI    128
#define NCH   256
#define CHL   16        // HW_/NCH

__device__ __forceinline__ float b2f(u16 v){ return __uint_as_float(((unsigned)v)<<16); }
__device__ __forceinline__ u16 f2b(float x){
  unsigned u = __float_as_uint(x);
  u += 0x7fff + ((u >> 16) & 1);      // RTNE
  return (u16)(u >> 16);
}
__device__ __forceinline__ float gelu_exact(float x){ return 0.5f*x*(1.0f+erff(x*0.70710678118654752f)); }
__device__ __forceinline__ float leaky02(float x){ return x>0.f ? x : 0.2f*x; }
__device__ __forceinline__ float softplus_(float x){ return fmaxf(x,0.f)+log1pf(__expf(-fabsf(x))); }
__device__ __forceinline__ float silu_(float x){ return x / (1.0f + __expf(-x)); }
__device__ __forceinline__ void unpack16(uint4 q0, uint4 q1, float* v){
  unsigned w[8]={q0.x,q0.y,q0.z,q0.w,q1.x,q1.y,q1.z,q1.w};
  #pragma unroll
  for(int j=0;j<8;j++){
    v[2*j]   = __uint_as_float(w[j]<<16);
    v[2*j+1] = __uint_as_float(w[j]&0xffff0000u);
  }
}

// ====== prep: all weights -> bf16 transposed [COUT][CIN]; W2 fused (xproj/dtw) ======
__global__ void k_prep(const float* __restrict__ vin_w1, const float* __restrict__ vin_w2,
                       const float* __restrict__ ssm_in_w, const float* __restrict__ xproj,
                       const float* __restrict__ dtw, const float* __restrict__ ssm_outw,
                       const float* __restrict__ ff_w1, const float* __restrict__ ff_w2,
                       u16* __restrict__ wv1, u16* __restrict__ wv2, u16* __restrict__ wsi,
                       u16* __restrict__ wdb, u16* __restrict__ wout, u16* __restrict__ wf1,
                       u16* __restrict__ wf2t){
  int g = blockIdx.x*256 + threadIdx.x;     // 80*256 = 20480
  if(g < 4096){
    int n=g>>6, c=g&63;
    wv1[n*64+c]=f2b(vin_w1[c*64+n]);
    wv2[n*64+c]=f2b(vin_w2[c*64+n]);
  }
  if(g < 16384){
    int n=g>>6, c=g&63;
    wsi[n*64+c]=f2b(ssm_in_w[c*256+n]);
    wf1[n*64+c]=f2b(ff_w1[c*256+n]);
    int n2=g/256, k2=g%256;
    wf2t[n2*256+k2]=f2b(ff_w2[k2*64+n2]);
  }
  if(g < 8192){
    int n=g>>7, k=g&127;
    wout[n*128+k]=f2b(ssm_outw[k*64+n]);
  }
  if(g < 20480){
    int n=g/128, k=g%128;
    float v;
    if(n < 128){
      v = 0.f;
      for(int r=0;r<4;r++) v += xproj[k*36+r]*dtw[r*128+n];
    }else{
      v = xproj[k*36+4+(n-128)];
    }
    wdb[n*128+k]=f2b(v);
  }
}

// ====== fused: NCHW fp32 -> (xT bf16 NHWC) + LayerNorm + vin_w1 MFMA -> outp ======
__global__ __launch_bounds__(256) void k_trans_ln_mm(const float* __restrict__ x,
                     const float* __restrict__ g, const float* __restrict__ bta,
                     const u16* __restrict__ wT,
                     u16* __restrict__ xT, u16* __restrict__ outp){
  const int LDA = 72, NS = 4;
  __shared__ float tile[64][65];
  __shared__ __align__(16) u16 sA[64*LDA];
  __shared__ __align__(16) u16 sW[64*LDA];
  int tid = threadIdx.x;
  int blk = blockIdx.x;            // 512
  int b = blk >> 6;
  int hwb = (blk & 63) << 6;
  int lane = tid & 63, row = tid >> 6;
  const float* src = x + (size_t)b*C_*HW_;
  #pragma unroll
  for(int k=0;k<16;k++){
    int c = row + 4*k;
    tile[c][lane] = src[c*HW_ + hwb + lane];
  }
  for(int idx=tid; idx<64*8; idx+=256){
    int n = idx>>3, c8 = (idx&7)*8;
    *(uint4*)(sW + n*LDA + c8) = *(const uint4*)(wT + n*64 + c8);
  }
  __syncthreads();
  u16* dstT = xT + (size_t)b*HW_*C_;
  #pragma unroll
  for(int k=0;k<16;k++){
    int hwl = row + 4*k;
    dstT[(hwb+hwl)*C_ + lane] = f2b(tile[lane][hwl]);
  }
  float gg = g[lane], bb = bta[lane];
  #pragma unroll
  for(int i=0;i<16;i++){
    int hwl = row*16 + i;
    float v = tile[lane][hwl];
    float s = v, sq = v*v;
    #pragma unroll
    for(int o=32;o>0;o>>=1){ s += __shfl_xor(s,o); sq += __shfl_xor(sq,o); }
    float m = s*(1.f/64.f);
    float var = sq*(1.f/64.f) - m*m;
    float r = rsqrtf(var + 1e-5f);
    sA[hwl*LDA + lane] = f2b((v-m)*r*gg + bb);
  }
  __syncthreads();
  int ln = tid & 63, wv = tid >> 6;
  int mrow = ln & 15, quad = ln >> 4;
  f4v acc[NS];
  #pragma unroll
  for(int i=0;i<NS;i++) acc[i] = (f4v){0.f,0.f,0.f,0.f};
  const u16* aBase = sA + (wv*16 + mrow)*LDA + quad*8;
  const u16* wBase = sW + mrow*LDA + quad*8;
  #pragma unroll
  for(int kk=0; kk<64; kk+=32){
    s8v af = *(const s8v*)(aBase + kk);
    #pragma unroll
    for(int ns=0; ns<NS; ns++){
      s8v bf = *(const s8v*)(wBase + ns*16*LDA + kk);
      acc[ns] = __builtin_amdgcn_mfma_f32_16x16x32_bf16(af, bf, acc[ns], 0, 0, 0);
    }
  }
  int p0 = blk*64;
  int pr = p0 + wv*16 + quad*4;
  #pragma unroll
  for(int ns=0; ns<NS; ns++){
    int n = ns*16 + mrow;
    #pragma unroll
    for(int r=0;r<4;r++)
      outp[(size_t)(pr+r)*64 + n] = f2b(acc[ns][r]);
  }
}

// ====== fused vin: dw3+gelu + 1x1 (wv2) MFMA; 512 blocks, 8x8 tile ======
__global__ __launch_bounds__(256) void k_dw3mm(const u16* __restrict__ in,
                     const float* __restrict__ dwgt, const u16* __restrict__ wT,
                     u16* __restrict__ x0){
  const int LDT = 72;
  __shared__ __align__(16) u16 sIn[10*10*64];    // 12.8 KB
  __shared__ __align__(16) u16 sT[64*LDT];       // 9.2 KB
  __shared__ __align__(16) u16 sW[64*LDT];       // 9.2 KB
  int tid = threadIdx.x;
  int blk = blockIdx.x;            // 512
  int b = blk >> 6;
  int t6 = blk & 63;
  int h0 = (t6 >> 3) * 8, w0 = (t6 & 7) * 8;
  for(int idx=tid; idx<64*8; idx+=256){
    int n = idx>>3, c8 = (idx&7)*8;
    *(uint4*)(sW + n*LDT + c8) = *(const uint4*)(wT + n*64 + c8);
  }
  for(int q=tid; q<10*10*16; q+=256){
    int pp = q >> 4, c4 = q & 15;
    int hh = pp / 10, ww = pp % 10;
    int gh = h0-1+hh, gw = w0-1+ww;
    ushort4 v = make_ushort4(0,0,0,0);
    if((unsigned)gh < 64u && (unsigned)gw < 64u)
      v = *(const ushort4*)(in + (size_t)((b*64+gh)*64+gw)*64 + c4*4);
    *(ushort4*)(sIn + pp*64 + c4*4) = v;
  }
  __syncthreads();
  int c4 = tid & 15;
  #pragma unroll
  for(int pass=0; pass<4; pass++){
    int opix = pass*16 + (tid>>4);
    int oh = opix >> 3, ow = opix & 7;
    float a0=0.f,a1=0.f,a2=0.f,a3=0.f;
    #pragma unroll
    for(int kh=0;kh<3;kh++){
      #pragma unroll
      for(int kw=0;kw<3;kw++){
        ushort4 v = *(const ushort4*)(sIn + ((oh+kh)*10 + (ow+kw))*64 + c4*4);
        float4 wv = *(const float4*)(dwgt + (kh*3+kw)*64 + c4*4);
        a0 += b2f(v.x)*wv.x; a1 += b2f(v.y)*wv.y;
        a2 += b2f(v.z)*wv.z; a3 += b2f(v.w)*wv.w;
      }
    }
    ushort4 o; o.x=f2b(gelu_exact(a0)); o.y=f2b(gelu_exact(a1));
    o.z=f2b(gelu_exact(a2)); o.w=f2b(gelu_exact(a3));
    *(ushort4*)(sT + opix*LDT + c4*4) = o;
  }
  __syncthreads();
  int ln = tid & 63, wv = tid >> 6;
  int mrow = ln & 15, quad = ln >> 4;
  f4v acc[4];
  #pragma unroll
  for(int i=0;i<4;i++) acc[i] = (f4v){0.f,0.f,0.f,0.f};
  const u16* aBase = sT + (wv*16 + mrow)*LDT + quad*8;
  const u16* wBase = sW + mrow*LDT + quad*8;
  #pragma unroll
  for(int kk=0; kk<64; kk+=32){
    s8v af = *(const s8v*)(aBase + kk);
    #pragma unroll
    for(int ns=0; ns<4; ns++){
      s8v bf = *(const s8v*)(wBase + ns*16*LDT + kk);
      acc[ns] = __builtin_amdgcn_mfma_f32_16x16x32_bf16(af, bf, acc[ns], 0, 0, 0);
    }
  }
  #pragma unroll
  for(int ns=0; ns<4; ns++){
    int n = ns*16 + mrow;
    #pragma unroll
    for(int r=0;r<4;r++){
      int opix = wv*16 + quad*4 + r;
      int oh = opix >> 3, ow = opix & 7;
      size_t p = ((size_t)(b*64 + h0+oh)*64 + (w0+ow));
      x0[p*64 + n] = f2b(acc[ns][r]);
    }
  }
}

// ====== fused: ssm_in matmul + causal conv + silu + dt/bc MFMA (xi tile stays in LDS) ======
__global__ __launch_bounds__(256) void k_ssm_dtbc(const u16* __restrict__ wT,
                     const u16* __restrict__ x0,
                     const float* __restrict__ cw, const float* __restrict__ cb,
                     const u16* __restrict__ wdb, const float* __restrict__ dtbias,
                     u16* __restrict__ xi, u16* __restrict__ zs,
                     u16* __restrict__ dtout, u16* __restrict__ bcout){
  const int LDA=72, NS=16, LDY=136, LDWD=136, NS2=10;
  __shared__ __align__(16) u16 S[31616];
  u16* sW   = S;
  u16* sA   = S + 18432;
  u16* ubuf = S + 23040;
  u16* xiT  = S;
  u16* wdbS = S + 8704;
  int tid = threadIdx.x;
  int p0 = blockIdx.x*64;
  int ln = tid & 63, wv = tid >> 6;
  int mrow = ln & 15, quad = ln >> 4;
  for(int idx=tid; idx<256*8; idx+=256){
    int n = idx>>3, c8 = (idx&7)*8;
    *(uint4*)(sW + n*LDA + c8) = *(const uint4*)(wT + n*64 + c8);
  }
  for(int g=tid; g<64*8; g+=256){
    int row = g >> 3, c8 = (g & 7)*8;
    *(uint4*)(sA + row*LDA + c8) = *(const uint4*)(x0 + (size_t)(p0+row)*64 + c8);
  }
  __syncthreads();
  f4v acc[NS];
  #pragma unroll
  for(int i=0;i<NS;i++) acc[i] = (f4v){0.f,0.f,0.f,0.f};
  const u16* aBase = sA + (wv*16 + mrow)*LDA + quad*8;
  const u16* wBase = sW + mrow*LDA + quad*8;
  #pragma unroll
  for(int kk=0; kk<64; kk+=32){
    s8v af = *(const s8v*)(aBase + kk);
    #pragma unroll
    for(int ns=0; ns<NS; ns++){
      s8v bf = *(const s8v*)(wBase + ns*16*LDA + kk);
      acc[ns] = __builtin_amdgcn_mfma_f32_16x16x32_bf16(af, bf, acc[ns], 0, 0, 0);
    }
  }
  bool bstart = ((p0 & 4095) == 0);
  for(int idx=tid; idx<384; idx+=256){
    int j = idx >> 7, n = idx & 127;
    float a2 = 0.f;
    if(!bstart){
      const u16* xr = x0 + (size_t)(p0-3+j)*64;
      #pragma unroll 8
      for(int c=0;c<64;c++) a2 += b2f(xr[c]) * b2f(sW[n*LDA+c]);
    }
    ubuf[j*128 + n] = f2b(a2);
  }
  int prl = wv*16 + quad*4;
  #pragma unroll
  for(int ns=0; ns<NS; ns++){
    int n = ns*16 + mrow;
    if(n < 128){
      #pragma unroll
      for(int r=0;r<4;r++) ubuf[(prl+r+3)*128 + n] = f2b(acc[ns][r]);
    }else{
      #pragma unroll
      for(int r=0;r<4;r++) zs[(size_t)(p0+prl+r)*128 + (n-128)] = f2b(silu_(acc[ns][r]));
    }
  }
  __syncthreads();   // ubuf complete; sW/sA now dead
  int d4 = tid & 31;
  float4 cbv = *(const float4*)(cb + d4*4);
  for(int row = tid >> 5; row < 64; row += 8){
    float a0=cbv.x, a1=cbv.y, a2=cbv.z, a3=cbv.w;
    #pragma unroll
    for(int k=0;k<4;k++){
      ushort4 v = *(const ushort4*)(ubuf + (row+k)*128 + d4*4);
      float4 wv4 = *(const float4*)(cw + k*128 + d4*4);
      a0 += b2f(v.x)*wv4.x; a1 += b2f(v.y)*wv4.y;
      a2 += b2f(v.z)*wv4.z; a3 += b2f(v.w)*wv4.w;
    }
    ushort4 o; o.x=f2b(silu_(a0)); o.y=f2b(silu_(a1)); o.z=f2b(silu_(a2)); o.w=f2b(silu_(a3));
    *(ushort4*)(xi + (size_t)(p0+row)*128 + d4*4) = o;
    *(ushort4*)(xiT + row*LDY + d4*4) = o;
  }
  __syncthreads();   // ubuf dead; xiT complete
  for(int idx=tid; idx<160*16; idx+=256){
    int n = idx>>4, c8 = (idx&15)*8;
    *(uint4*)(wdbS + n*LDWD + c8) = *(const uint4*)(wdb + n*128 + c8);
  }
  __syncthreads();
  f4v acc2[NS2];
  #pragma unroll
  for(int i=0;i<NS2;i++) acc2[i] = (f4v){0.f,0.f,0.f,0.f};
  #pragma unroll
  for(int kk=0; kk<128; kk+=32){
    s8v af = *(const s8v*)(xiT + (wv*16+mrow)*LDY + kk + quad*8);
    #pragma unroll
    for(int ns=0; ns<NS2; ns++){
      s8v bf = *(const s8v*)(wdbS + (ns*16+mrow)*LDWD + kk + quad*8);
      acc2[ns] = __builtin_amdgcn_mfma_f32_16x16x32_bf16(af, bf, acc2[ns], 0, 0, 0);
    }
  }
  int pr = p0 + wv*16 + quad*4;
  #pragma unroll
  for(int ns=0; ns<NS2; ns++){
    int n = ns*16 + mrow;
    if(n < 128){
      float bs = dtbias[n];
      #pragma unroll
      for(int r=0;r<4;r++)
        dtout[(size_t)(pr+r)*128 + n] = f2b(softplus_(acc2[ns][r] + bs));
    }else{
      #pragma unroll
      for(int r=0;r<4;r++)
        bcout[(size_t)(pr+r)*32 + (n-128)] = f2b(acc2[ns][r]);
    }
  }
}

// ====== scan phase 1: LDS-free, 1 chunk/thread, high occupancy ======
__global__ __launch_bounds__(256) void k_scan1(const u16* __restrict__ dt, const u16* __restrict__ xi,
                        const u16* __restrict__ bc, const float* __restrict__ alog,
                        u16* __restrict__ Pb, u16* __restrict__ Qb){
  int t = blockIdx.x*256 + threadIdx.x;    // 1024 blocks
  int d = t & 127;
  int ch = (t >> 7) & 255;
  int b = t >> 15;
  int pbase = b*HW_ + ch*CHL;
  float A[16];
  #pragma unroll
  for(int s=0;s<16;s++) A[s] = -__expf(alog[d*16+s]);
  float dtv[16], uv[16];
  #pragma unroll
  for(int i=0;i<CHL;i++){
    dtv[i] = b2f(dt[(size_t)(pbase+i)*128 + d]);
    uv[i]  = dtv[i] * b2f(xi[(size_t)(pbase+i)*128 + d]);
  }
  float Q[16], sumdt = 0.f;
  #pragma unroll
  for(int s=0;s<16;s++) Q[s] = 0.f;
  #pragma unroll
  for(int i=0;i<CHL;i++){
    float Bv[16];
    unpack16(*(const uint4*)(bc + (size_t)(pbase+i)*32),
             *(const uint4*)(bc + (size_t)(pbase+i)*32 + 8), Bv);
    sumdt += dtv[i];
    #pragma unroll
    for(int s=0;s<16;s++){
      float a = __expf(dtv[i]*A[s]);
      Q[s] = a*Q[s] + uv[i]*Bv[s];
    }
  }
  int gidx = ch*16384 + (b*128+d)*16;
  unsigned pw[8], qw[8];
  #pragma unroll
  for(int j=0;j<8;j++){
    pw[j] = (unsigned)f2b(__expf(A[2*j]*sumdt)) | ((unsigned)f2b(__expf(A[2*j+1]*sumdt))<<16);
    qw[j] = (unsigned)f2b(Q[2*j]) | ((unsigned)f2b(Q[2*j+1])<<16);
  }
  *(uint4*)(Pb+gidx)   = make_uint4(pw[0],pw[1],pw[2],pw[3]);
  *(uint4*)(Pb+gidx+8) = make_uint4(pw[4],pw[5],pw[6],pw[7]);
  *(uint4*)(Qb+gidx)   = make_uint4(qw[0],qw[1],qw[2],qw[3]);
  *(uint4*)(Qb+gidx+8) = make_uint4(qw[4],qw[5],qw[6],qw[7]);
}

// ---------------- scan phase 2: block-level 2-pass affine scan ----------------
__global__ __launch_bounds__(256) void k_scan2(const u16* __restrict__ Pb, const u16* __restrict__ Qb,
                        u16* __restrict__ Hin){
  __shared__ __align__(16) u16 sP[256*32];   // 16 KB
  __shared__ __align__(16) u16 sQ[256*32];   // 16 KB
  __shared__ float gP[8*32];
  __shared__ float gQ[8*32];
  int tid = threadIdx.x;
  int s0 = blockIdx.x * 32;                  // 512 blocks over 16384 sequences
  for(int idx = tid; idx < 256*4; idx += 256){
    int ch = idx >> 2, j8 = (idx & 3) * 8;
    *(uint4*)(sP + ch*32 + j8) = *(const uint4*)(Pb + (size_t)ch*16384 + s0 + j8);
    *(uint4*)(sQ + ch*32 + j8) = *(const uint4*)(Qb + (size_t)ch*16384 + s0 + j8);
  }
  __syncthreads();
  int sl = tid & 31, grp = tid >> 5;         // 8 groups x 32 chunks each
  int base = grp * 32;
  float P = 1.f, Q = 0.f;
  #pragma unroll 8
  for(int c = 0; c < 32; c++){
    float p = b2f(sP[(base+c)*32 + sl]);
    float q = b2f(sQ[(base+c)*32 + sl]);
    P = p * P;
    Q = p * Q + q;
  }
  gP[grp*32 + sl] = P;
  gQ[grp*32 + sl] = Q;
  __syncthreads();
  float h = 0.f;                             // exclusive group prefix (h0 = 0)
  #pragma unroll
  for(int g = 0; g < 7; g++){
    if(g < grp) h = gP[g*32 + sl] * h + gQ[g*32 + sl];
  }
  for(int c = 0; c < 32; c++){
    Hin[(size_t)(base+c)*16384 + s0 + sl] = f2b(h);
    float p = b2f(sP[(base+c)*32 + sl]);
    float q = b2f(sQ[(base+c)*32 + sl]);
    h = p * h + q;
  }
}

// ------- scan phase 3 (global column loads) + out-proj MFMA -------
__global__ __launch_bounds__(128) void k_scan3_mm(const u16* __restrict__ dt, const u16* __restrict__ xi,
                        const u16* __restrict__ bc, const u16* __restrict__ zs,
                        const float* __restrict__ alog, const float* __restrict__ Dp,
                        const u16* __restrict__ Hin, const u16* __restrict__ wout,
                        const u16* __restrict__ x0, u16* __restrict__ y){
  const int LDY = 136, LDW = 136;
  int blk = blockIdx.x;
  int ch = blk & (NCH-1);
  int b = blk >> 8;
  int d = threadIdx.x, tid = threadIdx.x;
  __shared__ __align__(16) u16 sY[CHL*LDY];
  __shared__ __align__(16) u16 sWo[64*LDW];
  __shared__ __align__(16) u16 sbc[CHL*32];
  for(int idx=tid; idx<64*16; idx+=128){
    int n = idx>>4, c8 = (idx&15)*8;
    *(uint4*)(sWo + n*LDW + c8) = *(const uint4*)(wout + n*128 + c8);
  }
  int pbase = b*HW_ + ch*CHL;
  if(tid < 64) ((uint4*)sbc)[tid] = ((const uint4*)(bc + (size_t)pbase*32))[tid];
  float A[16], h[16];
  u16 hbuf[16];
  int gidx = ch*16384 + (b*128+d)*16;
  *(uint4*)hbuf     = *(const uint4*)(Hin+gidx);
  *(uint4*)(hbuf+8) = *(const uint4*)(Hin+gidx+8);
  #pragma unroll
  for(int s=0;s<16;s++){ A[s] = -__expf(alog[d*16+s]); h[s] = b2f(hbuf[s]); }
  float Dd = Dp[d];
  float dtv[16], xiv[16], zsv[16];
  #pragma unroll
  for(int i=0;i<CHL;i++){
    dtv[i] = b2f(dt[(size_t)(pbase+i)*128 + d]);
    xiv[i] = b2f(xi[(size_t)(pbase+i)*128 + d]);
    zsv[i] = b2f(zs[(size_t)(pbase+i)*128 + d]);
  }
  __syncthreads();
  #pragma unroll
  for(int i=0;i<CHL;i++){
    float Bv[16], Cv[16];
    unpack16(*(const uint4*)(sbc + i*32),      *(const uint4*)(sbc + i*32 + 8),  Bv);
    unpack16(*(const uint4*)(sbc + i*32 + 16), *(const uint4*)(sbc + i*32 + 24), Cv);
    float u = dtv[i]*xiv[i];
    float acc = Dd*xiv[i];
    #pragma unroll
    for(int s=0;s<16;s++){
      float a = __expf(dtv[i]*A[s]);
      h[s] = a*h[s] + u*Bv[s];
      acc += h[s]*Cv[s];
    }
    sY[i*LDY + d] = f2b(acc * zsv[i]);
  }
  __syncthreads();
  int ln = tid & 63, wv = tid >> 6;
  int mrow = ln & 15, quad = ln >> 4;
  f4v acc2[2];
  acc2[0] = (f4v){0.f,0.f,0.f,0.f};
  acc2[1] = (f4v){0.f,0.f,0.f,0.f};
  #pragma unroll
  for(int kk=0; kk<128; kk+=32){
    s8v af = *(const s8v*)(sY + mrow*LDY + kk + quad*8);
    #pragma unroll
    for(int ns=0; ns<2; ns++){
      int n0 = wv*32 + ns*16;
      s8v bf = *(const s8v*)(sWo + (n0+mrow)*LDW + kk + quad*8);
      acc2[ns] = __builtin_amdgcn_mfma_f32_16x16x32_bf16(af, bf, acc2[ns], 0, 0, 0);
    }
  }
  #pragma unroll
  for(int ns=0; ns<2; ns++){
    int n = wv*32 + ns*16 + mrow;
    #pragma unroll
    for(int r=0;r<4;r++){
      int px = pbase + quad*4 + r;
      y[(size_t)px*64 + n] = f2b(acc2[ns][r] + b2f(x0[(size_t)px*64 + n]));
    }
  }
}

// ====== fully-fused tail: vout (dw2(gelu(dw1(y)))+y+xT) + FFN (LN+mm1+dw+mm2+res) ======
// per 8x8 tile: y 14x14 halo -> t 12x12 -> raw xR 10x10 (center 8x8 stashed) -> in-place LN
// -> 4 chunks of 64 mid-channels: MFMA1 -> t1 LDS -> dw3 into MFMA2 A-frags -> MFMA2 acc.
// Dynamic LDS: 74304 B.
__global__ __launch_bounds__(256) void k_ffn2(const u16* __restrict__ yin,
                     const float* __restrict__ w1, const float* __restrict__ w2,
                     const u16* __restrict__ xTr,
                     const float* __restrict__ g, const float* __restrict__ bta,
                     const u16* __restrict__ wf1, const u16* __restrict__ wf2t,
                     const float* __restrict__ fdw, float* __restrict__ outp){
  const int LDX = 72;
  extern __shared__ __align__(16) u16 S[];
  u16* sX  = S;                    // [112][72]  raw xR then LN'd (rows 100..111 zero)
  u16* sC  = S + 8064;             // [64][72]   raw xR center 8x8 (epilogue residual)
  u16* sYh = S + 12672;            // [196][72]  y halo 14x14          (phase 1)
  u16* sT  = S + 26784;            // [144][72]  t = gelu(dw1(y)) 12x12 (phase 1)
  u16* sT1 = S + 12672;            // [112][72]  (phase 2, aliases sYh)
  u16* sW1 = S + 20736;            // [64][72]
  u16* sW2 = S + 25344;            // [64][72]
  float* sDW = (float*)(S + 29952);// [9*256] f32 (aliases sT)
  int tid = threadIdx.x;
  int blk = blockIdx.x;            // 512
  int b = blk >> 6;
  int t6 = blk & 63;
  int h0 = (t6 >> 3)*8, w0 = (t6 & 7)*8;
  int ln = tid & 63, wv = tid >> 6;
  int mrow = ln & 15, quad = ln >> 4;
  // phase 1a: load y 14x14 halo (zero outside image)
  for(int q=tid; q<196*16; q+=256){
    int pp = q >> 4, c4 = q & 15;
    int hh = pp / 14, ww = pp - hh*14;
    int gh = h0-3+hh, gw = w0-3+ww;
    ushort4 v = make_ushort4(0,0,0,0);
    if((unsigned)gh < 64u && (unsigned)gw < 64u)
      v = *(const ushort4*)(yin + (size_t)((b*64+gh)*64+gw)*64 + c4*4);
    *(ushort4*)(sYh + pp*LDX + c4*4) = v;
  }
  __syncthreads();
  // phase 1b: t = gelu(dw1(y)) on 12x12 (0 outside image)
  for(int q=tid; q<144*16; q+=256){
    int tpix = q >> 4, c4 = q & 15;
    int th = tpix / 12, tw = tpix - th*12;
    int gh = h0-2+th, gw = w0-2+tw;
    ushort4 o = make_ushort4(0,0,0,0);
    if((unsigned)gh < 64u && (unsigned)gw < 64u){
      float a0=0.f,a1=0.f,a2=0.f,a3=0.f;
      #pragma unroll
      for(int kh=0;kh<3;kh++){
        #pragma unroll
        for(int kw=0;kw<3;kw++){
          ushort4 v = *(const ushort4*)(sYh + ((th+kh)*14 + (tw+kw))*LDX + c4*4);
          float4 wv4 = *(const float4*)(w1 + (kh*3+kw)*64 + c4*4);
          a0 += b2f(v.x)*wv4.x; a1 += b2f(v.y)*wv4.y;
          a2 += b2f(v.z)*wv4.z; a3 += b2f(v.w)*wv4.w;
        }
      }
      o.x=f2b(gelu_exact(a0)); o.y=f2b(gelu_exact(a1));
      o.z=f2b(gelu_exact(a2)); o.w=f2b(gelu_exact(a3));
    }
    *(ushort4*)(sT + tpix*LDX + c4*4) = o;
  }
  __syncthreads();
  // phase 1c: raw xR = dw2(t)+y+xT on 10x10 -> sX; center 8x8 also -> sC
  for(int q=tid; q<100*16; q+=256){
    int xpix = q >> 4, c4 = q & 15;
    int xh = xpix / 10, xw = xpix - xh*10;
    int gh = h0-1+xh, gw = w0-1+xw;
    ushort4 o = make_ushort4(0,0,0,0);
    if((unsigned)gh < 64u && (unsigned)gw < 64u){
      float a0=0.f,a1=0.f,a2=0.f,a3=0.f;
      #pragma unroll
      for(int kh=0;kh<3;kh++){
        #pragma unroll
        for(int kw=0;kw<3;kw++){
          ushort4 v = *(const ushort4*)(sT + ((xh+kh)*12 + (xw+kw))*LDX + c4*4);
          float4 wv4 = *(const float4*)(w2 + (kh*3+kw)*64 + c4*4);
          a0 += b2f(v.x)*wv4.x; a1 += b2f(v.y)*wv4.y;
          a2 += b2f(v.z)*wv4.z; a3 += b2f(v.w)*wv4.w;
        }
      }
      ushort4 ry = *(const ushort4*)(sYh + ((xh+2)*14 + (xw+2))*LDX + c4*4);
      ushort4 rx = *(const ushort4*)(xTr + (size_t)((b*64+gh)*64+gw)*64 + c4*4);
      a0 += b2f(ry.x) + b2f(rx.x);
      a1 += b2f(ry.y) + b2f(rx.y);
      a2 += b2f(ry.z) + b2f(rx.z);
      a3 += b2f(ry.w) + b2f(rx.w);
      o.x=f2b(a0); o.y=f2b(a1); o.z=f2b(a2); o.w=f2b(a3);
    }
    *(ushort4*)(sX + xpix*LDX + c4*4) = o;
    if(xh>=1 && xh<=8 && xw>=1 && xw<=8)
      *(ushort4*)(sC + ((xh-1)*8 + (xw-1))*LDX + c4*4) = o;
  }
  __syncthreads();
  // sT dead: load dw weights into aliased region; LN sX in place
  for(int i=tid; i<9*64; i+=256) ((float4*)sDW)[i] = ((const float4*)fdw)[i];
  float gg = g[ln], bb = bta[ln];
  for(int hp = wv; hp < 112; hp += 4){
    u16 o = 0;
    if(hp < 100){
      int th = hp/10, tw = hp - th*10;
      int gh = h0-1+th, gw = w0-1+tw;
      if((unsigned)gh < 64u && (unsigned)gw < 64u){
        float v = b2f(sX[hp*LDX + ln]);
        float s = v, sq = v*v;
        #pragma unroll
        for(int o2=32;o2>0;o2>>=1){ s += __shfl_xor(s,o2); sq += __shfl_xor(sq,o2); }
        float m = s*(1.f/64.f);
        float var = sq*(1.f/64.f) - m*m;
        float r = rsqrtf(var + 1e-5f);
        o = f2b((v-m)*r*gg + bb);
      }
    }
    sX[hp*LDX + ln] = o;
  }
  // phase 2: 4 chunks of 64 mid-channels
  f4v acc2[4];
  #pragma unroll
  for(int i=0;i<4;i++) acc2[i] = (f4v){0.f,0.f,0.f,0.f};
  int p = wv*16 + mrow;           // dw pixel owned by this lane (A-fragment row)
  int oh = p >> 3, ow = p & 7;
  for(int c=0; c<4; c++){
    int nc0 = c*64;
    __syncthreads();    // prev chunk's MFMA2 done (and sX/sDW ready on c==0)
    for(int idx=tid; idx<64*8; idx+=256){
      int n = idx>>3, c8 = (idx&7)*8;
      *(uint4*)(sW1 + n*LDX + c8) = *(const uint4*)(wf1 + (size_t)(nc0+n)*64 + c8);
      *(uint4*)(sW2 + n*LDX + c8) = *(const uint4*)(wf2t + (size_t)n*256 + nc0 + c8);
    }
    __syncthreads();
    // MFMA1: t1[112 x 64] = leaky(sX @ sW1^T)
    for(int mt = wv; mt < 7; mt += 4){
      f4v a1[4];
      #pragma unroll
      for(int i=0;i<4;i++) a1[i] = (f4v){0.f,0.f,0.f,0.f};
      const u16* aB = sX + (mt*16 + mrow)*LDX + quad*8;
      const u16* wB = sW1 + mrow*LDX + quad*8;
      #pragma unroll
      for(int kk=0; kk<64; kk+=32){
        s8v af = *(const s8v*)(aB + kk);
        #pragma unroll
        for(int ns=0; ns<4; ns++){
          s8v bf = *(const s8v*)(wB + ns*16*LDX + kk);
          a1[ns] = __builtin_amdgcn_mfma_f32_16x16x32_bf16(af, bf, a1[ns], 0, 0, 0);
        }
      }
      #pragma unroll
      for(int ns=0; ns<4; ns++)
        #pragma unroll
        for(int r=0; r<4; r++)
          sT1[(mt*16 + quad*4 + r)*LDX + ns*16 + mrow] = f2b(leaky02(a1[ns][r]));
    }
    __syncthreads();
    // dw3 + leaky directly into MFMA2 A-fragments; accumulate MFMA2
    #pragma unroll
    for(int half=0; half<2; half++){
      int ch0 = half*32 + quad*8;
      float a[8];
      #pragma unroll
      for(int j=0;j<8;j++) a[j] = 0.f;
      #pragma unroll
      for(int kh=0;kh<3;kh++){
        #pragma unroll
        for(int kw=0;kw<3;kw++){
          s8v v = *(const s8v*)(sT1 + ((oh+kh)*10 + (ow+kw))*LDX + ch0);
          const float* wp = sDW + (kh*3+kw)*256 + nc0 + ch0;
          float4 w0v = *(const float4*)(wp);
          float4 w1v = *(const float4*)(wp+4);
          a[0] += b2f((u16)v[0])*w0v.x; a[1] += b2f((u16)v[1])*w0v.y;
          a[2] += b2f((u16)v[2])*w0v.z; a[3] += b2f((u16)v[3])*w0v.w;
          a[4] += b2f((u16)v[4])*w1v.x; a[5] += b2f((u16)v[5])*w1v.y;
          a[6] += b2f((u16)v[6])*w1v.z; a[7] += b2f((u16)v[7])*w1v.w;
        }
      }
      s8v af;
      #pragma unroll
      for(int j=0;j<8;j++) af[j] = (short)f2b(leaky02(a[j]));
      #pragma unroll
      for(int ns=0; ns<4; ns++){
        s8v bf = *(const s8v*)(sW2 + (ns*16 + mrow)*LDX + half*32 + quad*8);
        acc2[ns] = __builtin_amdgcn_mfma_f32_16x16x32_bf16(af, bf, acc2[ns], 0, 0, 0);
      }
    }
  }
  // epilogue: + residual xR (from sC), store fp32 NCHW
  int pe = wv*16 + quad*4;
  int eoh = pe >> 3, eow0 = pe & 7;
  #pragma unroll
  for(int ns=0; ns<4; ns++){
    int n = ns*16 + mrow;
    float4 v4;
    v4.x = acc2[ns][0] + b2f(sC[(pe+0)*LDX + n]);
    v4.y = acc2[ns][1] + b2f(sC[(pe+1)*LDX + n]);
    v4.z = acc2[ns][2] + b2f(sC[(pe+2)*LDX + n]);
    v4.w = acc2[ns][3] + b2f(sC[(pe+3)*LDX + n]);
    *(float4*)(outp + (size_t)b*C_*HW_ + (size_t)n*HW_ + (h0+eoh)*64 + (w0+eow0)) = v4;
  }
}

extern "C" void kernel_launch(void* const* d_in, const int* in_sizes, int n_in,
                              void* d_out, int out_size, void* d_ws, size_t ws_size,
                              hipStream_t stream) {
  const float* x        = (const float*)d_in[0];
  const float* ln1_g    = (const float*)d_in[1];
  const float* ln1_b    = (const float*)d_in[2];
  const float* vin_w1   = (const float*)d_in[3];
  const float* vin_dw   = (const float*)d_in[4];
  const float* vin_w2   = (const float*)d_in[5];
  const float* vout_dw1 = (const float*)d_in[6];
  const float* vout_dw2 = (const float*)d_in[7];
  const float* ssm_in_w = (const float*)d_in[8];
  const float* ssm_cw   = (const float*)d_in[9];
  const float* ssm_cb   = (const float*)d_in[10];
  const float* ssm_xprj = (const float*)d_in[11];
  const float* ssm_dtw  = (const float*)d_in[12];
  const float* ssm_dtb  = (const float*)d_in[13];
  const float* ssm_Alog = (const float*)d_in[14];
  const float* ssm_D    = (const float*)d_in[15];
  const float* ssm_outw = (const float*)d_in[16];
  const float* ln2_g    = (const float*)d_in[17];
  const float* ln2_b    = (const float*)d_in[18];
  const float* ff_w1    = (const float*)d_in[19];
  const float* ff_dw    = (const float*)d_in[20];
  const float* ff_w2    = (const float*)d_in[21];
  float* out = (float*)d_out;

  // ---- bf16 arena, lifetime-packed (units: bf16 elements) ----
  const size_t M = 1u<<20;
  u16* U   = (u16*)d_ws;
  u16* xT  = U;              // [0,2M)
  u16* tA  = U + 2*M;        // [2M,4M)   Hin during scan
  u16* tB  = U + 4*M;        // [4M,6M)
  u16* x0  = U + 6*M;        // [6M,8M)
  u16* xi  = U + 8*M;        // [8M,12M)
  u16* zs  = U + 12*M;       // [12M,16M)
  u16* dtb = U + 24*M;       // [24M,28M) dt
  u16* bc  = U + 28*M;       // [28M,29M)
  u16* Pb  = U + 16*M;       // [16M,20M)
  u16* Qb  = U + 20*M;       // [20M,24M)
  u16* Hin = tA;             // [2M,6M)
  u16* y   = U + 16*M;       // [16M,18M)
  // pre-transposed bf16 weights:
  u16* wv1  = U + 33*M;
  u16* wv2  = wv1 + 4096;
  u16* wsi  = wv2 + 4096;
  u16* wdb  = wsi + 16384;
  u16* wout = wdb + 20480;
  u16* wf1  = wout + 8192;
  u16* wf2t = wf1 + 16384;

  static bool attr_set = false;
  if(!attr_set){
    hipFuncSetAttribute((const void*)k_ffn2,
                        hipFuncAttributeMaxDynamicSharedMemorySize, 74304);
    attr_set = true;
  }

  k_prep<<<80,256,0,stream>>>(vin_w1, vin_w2, ssm_in_w, ssm_xprj, ssm_dtw, ssm_outw,
                              ff_w1, ff_w2, wv1, wv2, wsi, wdb, wout, wf1, wf2t);

  // --- vision in path (dw3+gelu+vin_w2 fused, 512 blocks) ---
  k_trans_ln_mm<<<512,256,0,stream>>>(x, ln1_g, ln1_b, wv1, xT, tB);
  k_dw3mm<<<512,256,0,stream>>>(tB, vin_dw, wv2, x0);

  // --- SSM (ssm_in + conv + dt/bc fused; scan1 standalone for occupancy) ---
  k_ssm_dtbc<<<512,256,0,stream>>>(wsi, x0, ssm_cw, ssm_cb, wdb, ssm_dtb,
                                   xi, zs, dtb, bc);
  k_scan1<<<1024,256,0,stream>>>(dtb, xi, bc, ssm_Alog, Pb, Qb);
  k_scan2<<<512,256,0,stream>>>(Pb, Qb, Hin);
  k_scan3_mm<<<2048,128,0,stream>>>(dtb, xi, bc, zs, ssm_Alog, ssm_D, Hin, wout, x0, y);

  // --- fused tail: vout (dw pair + residuals) + FFN ---
  k_ffn2<<<512,256,74304,stream>>>(y, vout_dw1, vout_dw2, xT, ln2_g, ln2_b,
                                   wf1, wf2t, ff_dw, out);
}